// Round 2
// baseline (416.711 us; speedup 1.0000x reference)
//
#include <hip/hip_runtime.h>

// Problem: B=16, N=128, F=64, K=128, C=3 (all fp32)
//   pa = S @ w[:F]  (+ b)     -> (B*N, K)
//   pb = S @ w[F:]            -> (B*N, K)
//   out[b,i,j,c,k] = (pa[b,i,k] + pb[b,j,k]) * dist[b,i,j,c]
// out = 402.65 MB fp32 -> HBM-write-bound.
// Timed graph carries a fixed ~256 us harness poison fill; controllable floor
// is ~75 us (write roofline + proj). Key constraint on CDNA: loads and stores
// share one in-order vmcnt, so any in-loop global load wait drains the store
// queue. Fix: all in-loop reads come from LDS (lgkmcnt), stores stream free.

#define BN   2048      // B*N rows
#define FF   64        // F
#define KK   128       // K

typedef float f4 __attribute__((ext_vector_type(4)));

// Kernel A: per-row mini-GEMM. One block per row r (b*N+i), 128 threads = one k each.
// pa gets bias folded in. W columns (stride-128) are coalesced across k-threads;
// W (64 KB) is L2-resident after first block. (~5-10 us, verified.)
__global__ __launch_bounds__(128) void proj_kernel(
    const float* __restrict__ S,   // (BN, F)
    const float* __restrict__ W,   // (2F, K)
    const float* __restrict__ bias,// (K,)
    float* __restrict__ pa,        // (BN, K)  = S@W[:F] + bias
    float* __restrict__ pb)        // (BN, K)  = S@W[F:]
{
    __shared__ float s[FF];
    const int r = blockIdx.x;
    const int k = threadIdx.x;
    if (k < FF) s[k] = S[r * FF + k];
    __syncthreads();

    float acc_a = bias[k];
    float acc_b = 0.0f;
#pragma unroll
    for (int f = 0; f < FF; ++f) {
        const float sv = s[f];                 // LDS broadcast, conflict-free
        acc_a = fmaf(sv, W[f * KK + k], acc_a);
        acc_b = fmaf(sv, W[(f + FF) * KK + k], acc_b);
    }
    pa[r * KK + k] = acc_a;
    pb[r * KK + k] = acc_b;
}

// Kernel B: expansion as a pure streaming-store loop.
// One block per (b,i) = 2048 blocks, 384 threads (6 waves).
// Flat float4 index f = it*384 + t, it = 0..31. Since 384 = 4*96:
//   j  = it*4 + jt,  jt = t/96 (loop-invariant)
//   c  = (t%96)>>5            (loop-invariant)
//   kq = (t%96)&31            (loop-invariant)
// pb[b,:,:] (64 KB) is staged into LDS in TWO 32 KB phases (j 0..63, 64..127)
// so static LDS stays at 33.5 KB -> 4 blocks/CU. Inner loop reads are LDS-only
// (lgkmcnt); global stores are never waited on inside the loop (vmcnt stays
// load/store-decoupled). dist row (1.5 KB) staged once, broadcast reads.
__global__ __launch_bounds__(384, 6) void expand_kernel(
    const float* __restrict__ dist,  // (B, N, N, C)
    const float* __restrict__ pa,    // (BN, K) incl. bias
    const float* __restrict__ pb,    // (BN, K)
    float* __restrict__ out)         // (B, N, N, C, K)
{
    const int bi = blockIdx.x;          // b*128 + i
    const int b  = bi >> 7;
    const int t  = threadIdx.x;         // 0..383

    __shared__ f4    pbs[64 * (KK / 4)];  // 32 KB: half the pb slab (64 j-rows)
    __shared__ float dls[384];            // dist[bi, :, :]

    const int jt = t / 96;              // 0..3
    const int rr = t - jt * 96;         // 0..95
    const int c  = rr >> 5;             // 0..2
    const int kq = rr & 31;             // 0..31

    const f4* __restrict__ pb_b = (const f4*)pb + (size_t)b * (KK * KK / 4);

    // ---- stage phase-1 half of pb (j = 0..63) + dist row ----
#pragma unroll
    for (int idx = t; idx < 64 * (KK / 4); idx += 384)
        pbs[idx] = pb_b[idx];
    dls[t] = dist[(size_t)bi * 384 + t];

    // pa fragment: loop-invariant register float4 (L2-resident, broadcast).
    const f4 p = ((const f4*)pa)[bi * (KK / 4) + kq];
    __syncthreads();

    const f4*    __restrict__ q_p   = &pbs[jt * (KK / 4) + kq];
    const float* __restrict__ dp    = &dls[jt * 3 + c];
    f4*          __restrict__ out_p = (f4*)out + (size_t)bi * 12288 + t;

    // ---- phase 1: j = 0..63 (it = 0..15) ----
#pragma unroll 8
    for (int it = 0; it < 16; ++it) {
        const f4    q = q_p[it * 128];      // ds_read_b128, conflict-free/broadcast
        const float d = dp[it * 12];        // ds_read_b32, uniform broadcast
        f4 o;
        o.x = (p.x + q.x) * d;
        o.y = (p.y + q.y) * d;
        o.z = (p.z + q.z) * d;
        o.w = (p.w + q.w) * d;
        out_p[it * 384] = o;                // streaming store, never waited on
    }

    // ---- stage phase-2 half of pb (j = 64..127) ----
    __syncthreads();                        // all waves done reading phase-1 buf
#pragma unroll
    for (int idx = t; idx < 64 * (KK / 4); idx += 384)
        pbs[idx] = pb_b[64 * (KK / 4) + idx];
    __syncthreads();

    // ---- phase 2: j = 64..127 (it = 16..31) ----
#pragma unroll 8
    for (int it = 16; it < 32; ++it) {
        const f4    q = q_p[(it - 16) * 128];
        const float d = dp[it * 12];
        f4 o;
        o.x = (p.x + q.x) * d;
        o.y = (p.y + q.y) * d;
        o.z = (p.z + q.z) * d;
        o.w = (p.w + q.w) * d;
        out_p[it * 384] = o;
    }
}

extern "C" void kernel_launch(void* const* d_in, const int* in_sizes, int n_in,
                              void* d_out, int out_size, void* d_ws, size_t ws_size,
                              hipStream_t stream) {
    const float* S    = (const float*)d_in[0];  // (16,128,64)
    const float* dist = (const float*)d_in[1];  // (16,128,128,3)
    const float* W    = (const float*)d_in[2];  // (128,128)
    const float* bias = (const float*)d_in[3];  // (128,)
    float* out = (float*)d_out;

    float* pa = (float*)d_ws;                   // BN*K floats = 1 MB
    float* pb = pa + (size_t)BN * KK;           // 1 MB

    proj_kernel<<<BN, 128, 0, stream>>>(S, W, bias, pa, pb);
    expand_kernel<<<BN, 384, 0, stream>>>(dist, pa, pb, out);
}